// Round 1
// baseline (417.344 us; speedup 1.0000x reference)
//
#include <hip/hip_runtime.h>

// out[b] = M[b] @ X[b] + bias2, where (X = x_in[b] as [192,16384])
//   G[b]  = X X^T (Gram) ; Wq'=w_q@w_split etc.; Wo2=w_out@w_proj; bias2=w_out@b_proj
//   Tk = Wk' G ; qn[d]=sqrt(Wq'[d] G Wq'[d]^T) ; kn[cc]=sqrt(Tk[cc]·Wk'[cc])
//   A = softmax_rows(Tk Wq'^T / (kn ⊗ qn)) ; M = Wo2 (A Wv')
// Heavy phases (Gram, final GEMM) use bf16 MFMA 16x16x32 with fp32 accum.

static constexpr int B_ = 8;
static constexpr int C_ = 192;
static constexpr int N_ = 16384;
static constexpr int CC2 = C_ * C_;
static constexpr int NCHUNK = 32;

using u16x8 = __attribute__((ext_vector_type(8))) unsigned short;
using bf16x8 = __attribute__((ext_vector_type(8))) __bf16;
using f32x4 = __attribute__((ext_vector_type(4))) float;
using uint32x4 = __attribute__((ext_vector_type(4))) unsigned int;

__device__ __forceinline__ unsigned short f2bf(float f) {
  unsigned int u = __builtin_bit_cast(unsigned int, f);
  u += 0x7FFFu + ((u >> 16) & 1u);   // RNE
  return (unsigned short)(u >> 16);
}

// packed f32x2 -> bf16x2 (compiler emits v_cvt_pk_bf16_f32; RNE)
__device__ __forceinline__ unsigned int pkbf(float lo, float hi) {
  unsigned short a = __builtin_bit_cast(unsigned short, (__bf16)lo);
  unsigned short b = __builtin_bit_cast(unsigned short, (__bf16)hi);
  return (unsigned int)a | ((unsigned int)b << 16);
}

__device__ __forceinline__ float f4get(const float4& v, int e) {
  return (e == 0) ? v.x : (e == 1) ? v.y : (e == 2) ? v.z : v.w;
}

__device__ __forceinline__ f32x4 mfma16(u16x8 a, u16x8 b, f32x4 c) {
  return __builtin_amdgcn_mfma_f32_16x16x32_bf16(
      __builtin_bit_cast(bf16x8, a), __builtin_bit_cast(bf16x8, b), c, 0, 0, 0);
}

// ---------------- fold weights ----------------
__global__ void fold_kernel(const float* __restrict__ wsplit, const float* __restrict__ wq,
                            const float* __restrict__ wk, const float* __restrict__ wv,
                            const float* __restrict__ wproj, const float* __restrict__ bproj,
                            const float* __restrict__ wout,
                            float* __restrict__ Wq, float* __restrict__ WqT,
                            float* __restrict__ Wk, float* __restrict__ Wv,
                            float* __restrict__ Wo2, float* __restrict__ bias2) {
  int idx = blockIdx.x * 256 + threadIdx.x;
  if (idx < C_) {
    float s = 0.f;
    for (int c = 0; c < C_; ++c) s += wout[idx * C_ + c] * bproj[c];
    bias2[idx] = s;
  }
  if (idx >= 4 * CC2) return;
  int which = idx / CC2;
  int rem = idx % CC2;
  int o = rem / C_, c = rem % C_;
  const float* A = (which == 0) ? wq : (which == 1) ? wk : (which == 2) ? wv : wout;
  const float* Bm = (which == 3) ? wproj : wsplit;
  float s = 0.f;
  for (int e = 0; e < C_; ++e) s += A[o * C_ + e] * Bm[e * C_ + c];
  if (which == 0) { Wq[rem] = s; WqT[c * C_ + o] = s; }
  else if (which == 1) Wk[rem] = s;
  else if (which == 2) Wv[rem] = s;
  else Wo2[rem] = s;
}

// ---------------- Gram: row-split x2 for 2 blocks/CU, double-buffered pipeline ----------
// grid (32 k-chunks, 2 row-halves, 8 batches) = 512 blocks, 384 thr (6 waves).
// Each block stages all 192 X-rows but computes only its 96 G-rows (wave: 16 rows).
template <bool ATOMIC>
__global__ __launch_bounds__(384) void gram3_kernel(const float* __restrict__ xin,
                                                    float* __restrict__ dst) {
  const int b = blockIdx.z, half = blockIdx.y, ch = blockIdx.x;
  const int k0 = ch * 512;
  __shared__ unsigned short Xs[2][C_][72];         // dbuf, pitch 72 (2-way = free)
  const int tid = threadIdx.x;
  const int wv = tid >> 6;                         // 0..5
  const int lane = tid & 63;
  const int ln = lane & 15, mq = lane >> 4;
  const int arow0 = half * 96 + wv * 16;           // this wave's 16 G-rows
  const int cbase = tid >> 4;                      // 0..23
  const int k4 = tid & 15;
  const float* xb = xin + (size_t)b * C_ * N_;

  f32x4 acc[12];
#pragma unroll
  for (int j = 0; j < 12; ++j) acc[j] = (f32x4)0.0f;

  float4 ld[8];
  auto load_stage = [&](int kbase) {
#pragma unroll
    for (int j = 0; j < 8; ++j)
      ld[j] = *(const float4*)(xb + (size_t)(j * 24 + cbase) * N_ + kbase + k4 * 4);
  };
  auto write_stage = [&](int buf) {
#pragma unroll
    for (int j = 0; j < 8; ++j) {
      unsigned int lo = (unsigned)f2bf(ld[j].x) | ((unsigned)f2bf(ld[j].y) << 16);
      unsigned int hi = (unsigned)f2bf(ld[j].z) | ((unsigned)f2bf(ld[j].w) << 16);
      uint2 pk; pk.x = lo; pk.y = hi;
      *(uint2*)&Xs[buf][j * 24 + cbase][k4 * 4] = pk;    // ds_write_b64
    }
  };

  load_stage(k0);
  write_stage(0);
  __syncthreads();
  for (int s = 0; s < 8; ++s) {                    // 8 stages of 64 k
    if (s < 7) load_stage(k0 + (s + 1) * 64);      // prefetch overlaps MFMA
    const int cb = s & 1;
#pragma unroll
    for (int ks = 0; ks < 2; ++ks) {
      const int kk = ks * 32 + mq * 8;
      u16x8 a0 = *(const u16x8*)&Xs[cb][arow0 + ln][kk];
#pragma unroll
      for (int ct = 0; ct < 12; ++ct) {
        u16x8 bf = *(const u16x8*)&Xs[cb][ct * 16 + ln][kk];
        acc[ct] = mfma16(a0, bf, acc[ct]);
      }
    }
    if (s < 7) {
      write_stage(cb ^ 1);   // safe: cb^1 last read a full barrier ago
      __syncthreads();
    }
  }
  float* out = ATOMIC ? dst + (size_t)b * CC2
                      : dst + ((size_t)b * NCHUNK + ch) * CC2;
#pragma unroll
  for (int ct = 0; ct < 12; ++ct)
#pragma unroll
    for (int r = 0; r < 4; ++r) {
      int row = arow0 + mq * 4 + r;
      int col = ct * 16 + ln;
      if (ATOMIC) atomicAdd(&out[row * C_ + col], acc[ct][r]);
      else out[row * C_ + col] = acc[ct][r];
    }
}

// reduce 32 partials -> G. float4. grid (CC2/1024, 8), 256 thr.
__global__ void gsum_kernel(const float* __restrict__ P, float* __restrict__ G) {
  const int j = (blockIdx.x * 256 + threadIdx.x) * 4;
  const int b = blockIdx.y;
  const float* base = P + (size_t)b * NCHUNK * CC2 + j;
  float4 s = {0.f, 0.f, 0.f, 0.f};
#pragma unroll
  for (int ch = 0; ch < NCHUNK; ++ch) {
    float4 v = *(const float4*)(base + (size_t)ch * CC2);
    s.x += v.x; s.y += v.y; s.z += v.z; s.w += v.w;
  }
  *(float4*)(G + (size_t)b * CC2 + j) = s;
}

// ---------------- middle ----------------
// block (b,d): Tk row d = Wk[d]·G  AND  qn[b,d] = sqrt(Wq[d]·G·Wq[d]^T). Shares G reads.
__global__ __launch_bounds__(192) void tkqn_kernel(const float* __restrict__ Wk,
                                                   const float* __restrict__ Wq,
                                                   const float* __restrict__ G,
                                                   float* __restrict__ Tk,
                                                   float* __restrict__ qn) {
  const int b = blockIdx.y, d = blockIdx.x, t = threadIdx.x;
  const float* Gb = G + (size_t)b * CC2;
  float sk = 0.f, sq = 0.f;
  for (int c = 0; c < C_; ++c) {
    float g = Gb[c * C_ + t];
    sk += Wk[d * C_ + c] * g;
    sq += Wq[d * C_ + c] * g;
  }
  Tk[((size_t)b * C_ + d) * C_ + t] = sk;
  float val = sq * Wq[d * C_ + t];
  __shared__ float red[256];
  red[t] = val;
  if (t < 64) red[192 + t] = 0.f;
  __syncthreads();
  for (int st = 128; st > 0; st >>= 1) {
    if (t < st) red[t] += red[t + st];
    __syncthreads();
  }
  if (t == 0) qn[b * C_ + d] = fmaxf(sqrtf(fmaxf(red[0], 0.f)), 1e-12f);
}

// block (b,cc): kn + logits row + softmax + Tv row (A never materialized)
__global__ __launch_bounds__(192) void attn_av_kernel(const float* __restrict__ Tk,
                                                      const float* __restrict__ WqT,
                                                      const float* __restrict__ Wk,
                                                      const float* __restrict__ Wv,
                                                      const float* __restrict__ qn,
                                                      float* __restrict__ Tv) {
  const int b = blockIdx.y, cc = blockIdx.x, t = threadIdx.x;
  __shared__ float tkrow[C_];
  __shared__ float arow[C_];
  __shared__ float red[256];
  tkrow[t] = Tk[((size_t)b * C_ + cc) * C_ + t];
  red[t] = tkrow[t] * Wk[cc * C_ + t];
  if (t < 64) red[192 + t] = 0.f;
  __syncthreads();
  for (int st = 128; st > 0; st >>= 1) {
    if (t < st) red[t] += red[t + st];
    __syncthreads();
  }
  float knv = fmaxf(sqrtf(fmaxf(red[0], 0.f)), 1e-12f);
  __syncthreads();
  float s = 0.f;
  for (int c = 0; c < C_; ++c) s += tkrow[c] * WqT[c * C_ + t];
  float lg = s / (knv * qn[b * C_ + t]);
  red[t] = lg;
  if (t < 64) red[192 + t] = -1e30f;
  __syncthreads();
  for (int st = 128; st > 0; st >>= 1) {
    if (t < st) red[t] = fmaxf(red[t], red[t + st]);
    __syncthreads();
  }
  float mx = red[0];
  __syncthreads();
  float e = expf(lg - mx);
  red[t] = e;
  if (t < 64) red[192 + t] = 0.f;
  __syncthreads();
  for (int st = 128; st > 0; st >>= 1) {
    if (t < st) red[t] += red[t + st];
    __syncthreads();
  }
  float a = e / red[0];
  arow[t] = a;
  __syncthreads();
  float sv = 0.f;
  for (int c = 0; c < C_; ++c) sv += arow[c] * Wv[c * C_ + t];
  Tv[((size_t)b * C_ + cc) * C_ + t] = sv;
}

__global__ void m_kernel(const float* __restrict__ Wo2, const float* __restrict__ Tv,
                         float* __restrict__ Mout) {
  int idx = blockIdx.x * 256 + threadIdx.x;        // B*C*C
  if (idx >= B_ * CC2) return;
  int b = idx / CC2;
  int rc = idx % CC2;
  int i = rc / C_, j = rc % C_;
  float s = 0.f;
  for (int c = 0; c < C_; ++c) s += Wo2[i * C_ + c] * Tv[((size_t)b * C_ + c) * C_ + j];
  Mout[idx] = s;
}

// ---------------- final: out[b] = M[b] @ X[b] + bias2, bf16 MFMA ----------------
// v3: 64-px blocks (LDS 24 KB -> more residency, 2048 blocks -> finer granularity),
// 2-section (32 px) register-prefetch pipeline so section-1 HBM latency hides under
// section-0 MFMA, packed b64 LDS writes with v_cvt_pk_bf16_f32 (8 writes/thread vs
// 64 scalar b16), XOR swizzle key = (p>>1)&7 so per-instruction bank spread comes
// from pixel bits that vary across lanes (no runtime element rotation needed).
// LDS element (p, c) lives at Ts[p*192 + (((c>>3) ^ ((p>>1)&7))<<3) + (c&7)].
__global__ __launch_bounds__(384, 5) void final3_kernel(const float* __restrict__ xin,
                                                        const float* __restrict__ Mw,
                                                        const float* __restrict__ bias2,
                                                        float* __restrict__ out) {
  const int b = blockIdx.y;
  const int p0 = blockIdx.x * 64;
  __shared__ __align__(16) unsigned short Ts[64 * 192];   // 24 KB swizzled [p][c]
  const int tid = threadIdx.x;
  const int wv = tid >> 6;                         // 0..5, wave owns rows 32*wv..+31
  const int lane = tid & 63;
  const int ln = lane & 15, mq = lane >> 4;
  const float* Mb = Mw + (size_t)b * CC2;

  // staging map: c-quad c0 = (tid>>3)*4 (48 quads), px-quad pq = tid&7 (8 per section)
  const int c0 = (tid >> 3) * 4;
  const int pq = tid & 7;
  const float* xsrc = xin + ((size_t)b * C_ + c0) * N_ + p0 + pq * 4;

  float4 ldA[4], ldB[4];
#pragma unroll
  for (int l = 0; l < 4; ++l) ldA[l] = *(const float4*)(xsrc + (size_t)l * N_);

  // M fragments (bf16) + bias, loaded once per block
  u16x8 afr[6][2];
  float bo[2][4];
#pragma unroll
  for (int i = 0; i < 2; ++i) {
    int row = 32 * wv + 16 * i + ln;
#pragma unroll
    for (int kc = 0; kc < 6; ++kc) {
      const float* src = Mb + row * C_ + kc * 32 + mq * 8;
      float4 u0 = *(const float4*)(src);
      float4 u1 = *(const float4*)(src + 4);
      uint32x4 w;
      w[0] = pkbf(u0.x, u0.y); w[1] = pkbf(u0.z, u0.w);
      w[2] = pkbf(u1.x, u1.y); w[3] = pkbf(u1.z, u1.w);
      afr[kc][i] = __builtin_bit_cast(u16x8, w);
    }
#pragma unroll
    for (int r = 0; r < 4; ++r) bo[i][r] = bias2[32 * wv + 16 * i + mq * 4 + r];
  }

  auto stage_write = [&](const float4* ld, int sbase) {
#pragma unroll
    for (int e = 0; e < 4; ++e) {                  // e compile-time: direct .x/.y/.z/.w
      int p = sbase + pq * 4 + e;
      int idx = p * 192 + ((((c0 >> 3) ^ ((p >> 1) & 7)) << 3) | (c0 & 7));
      uint2 pk;
      pk.x = pkbf(f4get(ld[0], e), f4get(ld[1], e));
      pk.y = pkbf(f4get(ld[2], e), f4get(ld[3], e));
      *(uint2*)&Ts[idx] = pk;                      // ds_write_b64
    }
  };

  auto compute = [&](int pt) {
    const int p = pt * 16 + ln;
    const int pkey = (p >> 1) & 7;
    f32x4 acc0 = (f32x4)0.0f, acc1 = (f32x4)0.0f;
#pragma unroll
    for (int kc = 0; kc < 6; ++kc) {
      u16x8 bf = *(const u16x8*)&Ts[p * 192 + (((kc * 4 + mq) ^ pkey) << 3)];
      acc0 = mfma16(afr[kc][0], bf, acc0);
      acc1 = mfma16(afr[kc][1], bf, acc1);
    }
    const int pp = p0 + p;
#pragma unroll
    for (int r = 0; r < 4; ++r) {
      int row0 = 32 * wv + mq * 4 + r;
      out[((size_t)b * C_ + row0) * N_ + pp] = acc0[r] + bo[0][r];
      out[((size_t)b * C_ + row0 + 16) * N_ + pp] = acc1[r] + bo[1][r];
    }
  };

  stage_write(ldA, 0);
  __syncthreads();
#pragma unroll
  for (int l = 0; l < 4; ++l) ldB[l] = *(const float4*)(xsrc + 32 + (size_t)l * N_);
  compute(0);
  compute(1);
  stage_write(ldB, 32);                            // waits vmcnt here, after MFMA
  __syncthreads();
  compute(2);
  compute(3);
}

extern "C" void kernel_launch(void* const* d_in, const int* in_sizes, int n_in,
                              void* d_out, int out_size, void* d_ws, size_t ws_size,
                              hipStream_t stream) {
  const float* xin    = (const float*)d_in[0];
  const float* wsplit = (const float*)d_in[1];
  const float* wq     = (const float*)d_in[2];
  const float* wk     = (const float*)d_in[3];
  const float* wv     = (const float*)d_in[4];
  const float* wproj  = (const float*)d_in[5];
  const float* bproj  = (const float*)d_in[6];
  const float* wout   = (const float*)d_in[7];
  float* out = (float*)d_out;

  float* ws = (float*)d_ws;
  float* G     = ws;                         // B*CC2
  float* Wq    = G + (size_t)B_ * CC2;       // CC2
  float* WqT   = Wq + CC2;
  float* Wk    = WqT + CC2;
  float* Wv    = Wk + CC2;
  float* Wo2   = Wv + CC2;
  float* bias2 = Wo2 + CC2;                  // 256
  float* Tk    = bias2 + 256;                // B*CC2
  float* Tv    = Tk + (size_t)B_ * CC2;
  float* Mw    = Tv + (size_t)B_ * CC2;
  float* qn    = Mw + (size_t)B_ * CC2;      // B*C_ (pad 256)
  float* P     = qn + 256 * B_;              // B*NCHUNK*CC2 (37.7 MB) if it fits

  size_t base_floats = (size_t)(P - ws);
  size_t need_bytes = (base_floats + (size_t)B_ * NCHUNK * CC2) * sizeof(float);
  bool use_partials = ws_size >= need_bytes;

  fold_kernel<<<(4 * CC2 + 255) / 256, 256, 0, stream>>>(
      wsplit, wq, wk, wv, wproj, bproj, wout, Wq, WqT, Wk, Wv, Wo2, bias2);
  if (use_partials) {
    gram3_kernel<false><<<dim3(NCHUNK, 2, B_), 384, 0, stream>>>(xin, P);
    gsum_kernel<<<dim3(CC2 / 1024, B_), 256, 0, stream>>>(P, G);
  } else {
    hipMemsetAsync(G, 0, (size_t)B_ * CC2 * sizeof(float), stream);
    gram3_kernel<true><<<dim3(NCHUNK, 2, B_), 384, 0, stream>>>(xin, G);
  }
  tkqn_kernel<<<dim3(C_, B_), 192, 0, stream>>>(Wk, Wq, G, Tk, qn);
  attn_av_kernel<<<dim3(C_, B_), 192, 0, stream>>>(Tk, WqT, Wk, Wv, qn, Tv);
  m_kernel<<<(B_ * CC2 + 255) / 256, 256, 0, stream>>>(Wo2, Tv, Mw);
  final3_kernel<<<dim3(N_ / 64, B_), 384, 0, stream>>>(xin, Mw, bias2, out);
}

// Round 2
// 314.876 us; speedup vs baseline: 1.3254x; 1.3254x over previous
//
#include <hip/hip_runtime.h>

// out[b] = M[b] @ X[b] + bias2, where (X = x_in[b] as [192,16384])
//   G[b]  = X X^T (Gram) ; Wq'=w_q@w_split etc.; Wo2=w_out@w_proj; bias2=w_out@b_proj
//   Tk = Wk' G ; qn[d]=sqrt(Wq'[d] G Wq'[d]^T) ; kn[cc]=sqrt(Tk[cc]·Wk'[cc])
//   A = softmax_rows(Tk Wq'^T / (kn ⊗ qn)) ; M = Wo2 (A Wv')
// Heavy phases (Gram, final GEMM) use bf16 MFMA 16x16x32 with fp32 accum.

static constexpr int B_ = 8;
static constexpr int C_ = 192;
static constexpr int N_ = 16384;
static constexpr int CC2 = C_ * C_;
static constexpr int NCHUNK = 32;

using u16x8 = __attribute__((ext_vector_type(8))) unsigned short;
using bf16x8 = __attribute__((ext_vector_type(8))) __bf16;
using f32x4 = __attribute__((ext_vector_type(4))) float;
using uint32x4 = __attribute__((ext_vector_type(4))) unsigned int;

__device__ __forceinline__ unsigned short f2bf(float f) {
  unsigned int u = __builtin_bit_cast(unsigned int, f);
  u += 0x7FFFu + ((u >> 16) & 1u);   // RNE
  return (unsigned short)(u >> 16);
}

// packed f32x2 -> bf16x2 (compiler emits v_cvt_pk_bf16_f32; RNE)
__device__ __forceinline__ unsigned int pkbf(float lo, float hi) {
  unsigned short a = __builtin_bit_cast(unsigned short, (__bf16)lo);
  unsigned short b = __builtin_bit_cast(unsigned short, (__bf16)hi);
  return (unsigned int)a | ((unsigned int)b << 16);
}

__device__ __forceinline__ float f4get(const float4& v, int e) {
  return (e == 0) ? v.x : (e == 1) ? v.y : (e == 2) ? v.z : v.w;
}

__device__ __forceinline__ f32x4 mfma16(u16x8 a, u16x8 b, f32x4 c) {
  return __builtin_amdgcn_mfma_f32_16x16x32_bf16(
      __builtin_bit_cast(bf16x8, a), __builtin_bit_cast(bf16x8, b), c, 0, 0, 0);
}

// ---------------- fold weights ----------------
__global__ void fold_kernel(const float* __restrict__ wsplit, const float* __restrict__ wq,
                            const float* __restrict__ wk, const float* __restrict__ wv,
                            const float* __restrict__ wproj, const float* __restrict__ bproj,
                            const float* __restrict__ wout,
                            float* __restrict__ Wq, float* __restrict__ WqT,
                            float* __restrict__ Wk, float* __restrict__ Wv,
                            float* __restrict__ Wo2, float* __restrict__ bias2) {
  int idx = blockIdx.x * 256 + threadIdx.x;
  if (idx < C_) {
    float s = 0.f;
    for (int c = 0; c < C_; ++c) s += wout[idx * C_ + c] * bproj[c];
    bias2[idx] = s;
  }
  if (idx >= 4 * CC2) return;
  int which = idx / CC2;
  int rem = idx % CC2;
  int o = rem / C_, c = rem % C_;
  const float* A = (which == 0) ? wq : (which == 1) ? wk : (which == 2) ? wv : wout;
  const float* Bm = (which == 3) ? wproj : wsplit;
  float s = 0.f;
  for (int e = 0; e < C_; ++e) s += A[o * C_ + e] * Bm[e * C_ + c];
  if (which == 0) { Wq[rem] = s; WqT[c * C_ + o] = s; }
  else if (which == 1) Wk[rem] = s;
  else if (which == 2) Wv[rem] = s;
  else Wo2[rem] = s;
}

// ---------------- Gram: row-split x2 for 2 blocks/CU, double-buffered pipeline ----------
// grid (32 k-chunks, 2 row-halves, 8 batches) = 512 blocks, 384 thr (6 waves).
// Each block stages all 192 X-rows but computes only its 96 G-rows (wave: 16 rows).
template <bool ATOMIC>
__global__ __launch_bounds__(384) void gram3_kernel(const float* __restrict__ xin,
                                                    float* __restrict__ dst) {
  const int b = blockIdx.z, half = blockIdx.y, ch = blockIdx.x;
  const int k0 = ch * 512;
  __shared__ unsigned short Xs[2][C_][72];         // dbuf, pitch 72 (2-way = free)
  const int tid = threadIdx.x;
  const int wv = tid >> 6;                         // 0..5
  const int lane = tid & 63;
  const int ln = lane & 15, mq = lane >> 4;
  const int arow0 = half * 96 + wv * 16;           // this wave's 16 G-rows
  const int cbase = tid >> 4;                      // 0..23
  const int k4 = tid & 15;
  const float* xb = xin + (size_t)b * C_ * N_;

  f32x4 acc[12];
#pragma unroll
  for (int j = 0; j < 12; ++j) acc[j] = (f32x4)0.0f;

  float4 ld[8];
  auto load_stage = [&](int kbase) {
#pragma unroll
    for (int j = 0; j < 8; ++j)
      ld[j] = *(const float4*)(xb + (size_t)(j * 24 + cbase) * N_ + kbase + k4 * 4);
  };
  auto write_stage = [&](int buf) {
#pragma unroll
    for (int j = 0; j < 8; ++j) {
      unsigned int lo = (unsigned)f2bf(ld[j].x) | ((unsigned)f2bf(ld[j].y) << 16);
      unsigned int hi = (unsigned)f2bf(ld[j].z) | ((unsigned)f2bf(ld[j].w) << 16);
      uint2 pk; pk.x = lo; pk.y = hi;
      *(uint2*)&Xs[buf][j * 24 + cbase][k4 * 4] = pk;    // ds_write_b64
    }
  };

  load_stage(k0);
  write_stage(0);
  __syncthreads();
  for (int s = 0; s < 8; ++s) {                    // 8 stages of 64 k
    if (s < 7) load_stage(k0 + (s + 1) * 64);      // prefetch overlaps MFMA
    const int cb = s & 1;
#pragma unroll
    for (int ks = 0; ks < 2; ++ks) {
      const int kk = ks * 32 + mq * 8;
      u16x8 a0 = *(const u16x8*)&Xs[cb][arow0 + ln][kk];
#pragma unroll
      for (int ct = 0; ct < 12; ++ct) {
        u16x8 bf = *(const u16x8*)&Xs[cb][ct * 16 + ln][kk];
        acc[ct] = mfma16(a0, bf, acc[ct]);
      }
    }
    if (s < 7) {
      write_stage(cb ^ 1);   // safe: cb^1 last read a full barrier ago
      __syncthreads();
    }
  }
  float* out = ATOMIC ? dst + (size_t)b * CC2
                      : dst + ((size_t)b * NCHUNK + ch) * CC2;
#pragma unroll
  for (int ct = 0; ct < 12; ++ct)
#pragma unroll
    for (int r = 0; r < 4; ++r) {
      int row = arow0 + mq * 4 + r;
      int col = ct * 16 + ln;
      if (ATOMIC) atomicAdd(&out[row * C_ + col], acc[ct][r]);
      else out[row * C_ + col] = acc[ct][r];
    }
}

// reduce 32 partials -> G. float4. grid (CC2/1024, 8), 256 thr.
__global__ void gsum_kernel(const float* __restrict__ P, float* __restrict__ G) {
  const int j = (blockIdx.x * 256 + threadIdx.x) * 4;
  const int b = blockIdx.y;
  const float* base = P + (size_t)b * NCHUNK * CC2 + j;
  float4 s = {0.f, 0.f, 0.f, 0.f};
#pragma unroll
  for (int ch = 0; ch < NCHUNK; ++ch) {
    float4 v = *(const float4*)(base + (size_t)ch * CC2);
    s.x += v.x; s.y += v.y; s.z += v.z; s.w += v.w;
  }
  *(float4*)(G + (size_t)b * CC2 + j) = s;
}

// ---------------- middle ----------------
// block (b,d): Tk row d = Wk[d]·G  AND  qn[b,d] = sqrt(Wq[d]·G·Wq[d]^T). Shares G reads.
__global__ __launch_bounds__(192) void tkqn_kernel(const float* __restrict__ Wk,
                                                   const float* __restrict__ Wq,
                                                   const float* __restrict__ G,
                                                   float* __restrict__ Tk,
                                                   float* __restrict__ qn) {
  const int b = blockIdx.y, d = blockIdx.x, t = threadIdx.x;
  const float* Gb = G + (size_t)b * CC2;
  float sk = 0.f, sq = 0.f;
  for (int c = 0; c < C_; ++c) {
    float g = Gb[c * C_ + t];
    sk += Wk[d * C_ + c] * g;
    sq += Wq[d * C_ + c] * g;
  }
  Tk[((size_t)b * C_ + d) * C_ + t] = sk;
  float val = sq * Wq[d * C_ + t];
  __shared__ float red[256];
  red[t] = val;
  if (t < 64) red[192 + t] = 0.f;
  __syncthreads();
  for (int st = 128; st > 0; st >>= 1) {
    if (t < st) red[t] += red[t + st];
    __syncthreads();
  }
  if (t == 0) qn[b * C_ + d] = fmaxf(sqrtf(fmaxf(red[0], 0.f)), 1e-12f);
}

// block (b,cc): kn + logits row + softmax + Tv row (A never materialized)
__global__ __launch_bounds__(192) void attn_av_kernel(const float* __restrict__ Tk,
                                                      const float* __restrict__ WqT,
                                                      const float* __restrict__ Wk,
                                                      const float* __restrict__ Wv,
                                                      const float* __restrict__ qn,
                                                      float* __restrict__ Tv) {
  const int b = blockIdx.y, cc = blockIdx.x, t = threadIdx.x;
  __shared__ float tkrow[C_];
  __shared__ float arow[C_];
  __shared__ float red[256];
  tkrow[t] = Tk[((size_t)b * C_ + cc) * C_ + t];
  red[t] = tkrow[t] * Wk[cc * C_ + t];
  if (t < 64) red[192 + t] = 0.f;
  __syncthreads();
  for (int st = 128; st > 0; st >>= 1) {
    if (t < st) red[t] += red[t + st];
    __syncthreads();
  }
  float knv = fmaxf(sqrtf(fmaxf(red[0], 0.f)), 1e-12f);
  __syncthreads();
  float s = 0.f;
  for (int c = 0; c < C_; ++c) s += tkrow[c] * WqT[c * C_ + t];
  float lg = s / (knv * qn[b * C_ + t]);
  red[t] = lg;
  if (t < 64) red[192 + t] = -1e30f;
  __syncthreads();
  for (int st = 128; st > 0; st >>= 1) {
    if (t < st) red[t] = fmaxf(red[t], red[t + st]);
    __syncthreads();
  }
  float mx = red[0];
  __syncthreads();
  float e = expf(lg - mx);
  red[t] = e;
  if (t < 64) red[192 + t] = 0.f;
  __syncthreads();
  for (int st = 128; st > 0; st >>= 1) {
    if (t < st) red[t] += red[t + st];
    __syncthreads();
  }
  float a = e / red[0];
  arow[t] = a;
  __syncthreads();
  float sv = 0.f;
  for (int c = 0; c < C_; ++c) sv += arow[c] * Wv[c * C_ + t];
  Tv[((size_t)b * C_ + cc) * C_ + t] = sv;
}

__global__ void m_kernel(const float* __restrict__ Wo2, const float* __restrict__ Tv,
                         float* __restrict__ Mout) {
  int idx = blockIdx.x * 256 + threadIdx.x;        // B*C*C
  if (idx >= B_ * CC2) return;
  int b = idx / CC2;
  int rc = idx % CC2;
  int i = rc / C_, j = rc % C_;
  float s = 0.f;
  for (int c = 0; c < C_; ++c) s += Wo2[i * C_ + c] * Tv[((size_t)b * C_ + c) * C_ + j];
  Mout[idx] = s;
}

// ---------------- final: out[b] = M[b] @ X[b] + bias2, bf16 MFMA ----------------
// v3b: same as v3 but __launch_bounds__(384, 4): the ,5 variant forced VGPR=48 and
// spilled afr[6][2] (48 regs) + ld (16 regs) to scratch -> 250 B/thread of HBM spill
// traffic (FETCH 54->177 MB, WRITE 98->297 MB, dur 69->150 us). 512/4 = 128 VGPR
// budget comfortably fits the ~100-reg live set with zero spill, still >=16 waves/CU.
__global__ __launch_bounds__(384, 4) void final3_kernel(const float* __restrict__ xin,
                                                        const float* __restrict__ Mw,
                                                        const float* __restrict__ bias2,
                                                        float* __restrict__ out) {
  const int b = blockIdx.y;
  const int p0 = blockIdx.x * 64;
  __shared__ __align__(16) unsigned short Ts[64 * 192];   // 24 KB swizzled [p][c]
  const int tid = threadIdx.x;
  const int wv = tid >> 6;                         // 0..5, wave owns rows 32*wv..+31
  const int lane = tid & 63;
  const int ln = lane & 15, mq = lane >> 4;
  const float* Mb = Mw + (size_t)b * CC2;

  // staging map: c-quad c0 = (tid>>3)*4 (48 quads), px-quad pq = tid&7 (8 per section)
  const int c0 = (tid >> 3) * 4;
  const int pq = tid & 7;
  const float* xsrc = xin + ((size_t)b * C_ + c0) * N_ + p0 + pq * 4;

  float4 ldA[4], ldB[4];
#pragma unroll
  for (int l = 0; l < 4; ++l) ldA[l] = *(const float4*)(xsrc + (size_t)l * N_);

  // M fragments (bf16) + bias, loaded once per block
  u16x8 afr[6][2];
  float bo[2][4];
#pragma unroll
  for (int i = 0; i < 2; ++i) {
    int row = 32 * wv + 16 * i + ln;
#pragma unroll
    for (int kc = 0; kc < 6; ++kc) {
      const float* src = Mb + row * C_ + kc * 32 + mq * 8;
      float4 u0 = *(const float4*)(src);
      float4 u1 = *(const float4*)(src + 4);
      uint32x4 w;
      w[0] = pkbf(u0.x, u0.y); w[1] = pkbf(u0.z, u0.w);
      w[2] = pkbf(u1.x, u1.y); w[3] = pkbf(u1.z, u1.w);
      afr[kc][i] = __builtin_bit_cast(u16x8, w);
    }
#pragma unroll
    for (int r = 0; r < 4; ++r) bo[i][r] = bias2[32 * wv + 16 * i + mq * 4 + r];
  }

  auto stage_write = [&](const float4* ld, int sbase) {
#pragma unroll
    for (int e = 0; e < 4; ++e) {                  // e compile-time: direct .x/.y/.z/.w
      int p = sbase + pq * 4 + e;
      int idx = p * 192 + ((((c0 >> 3) ^ ((p >> 1) & 7)) << 3) | (c0 & 7));
      uint2 pk;
      pk.x = pkbf(f4get(ld[0], e), f4get(ld[1], e));
      pk.y = pkbf(f4get(ld[2], e), f4get(ld[3], e));
      *(uint2*)&Ts[idx] = pk;                      // ds_write_b64
    }
  };

  auto compute = [&](int pt) {
    const int p = pt * 16 + ln;
    const int pkey = (p >> 1) & 7;
    f32x4 acc0 = (f32x4)0.0f, acc1 = (f32x4)0.0f;
#pragma unroll
    for (int kc = 0; kc < 6; ++kc) {
      u16x8 bf = *(const u16x8*)&Ts[p * 192 + (((kc * 4 + mq) ^ pkey) << 3)];
      acc0 = mfma16(afr[kc][0], bf, acc0);
      acc1 = mfma16(afr[kc][1], bf, acc1);
    }
    const int pp = p0 + p;
#pragma unroll
    for (int r = 0; r < 4; ++r) {
      int row0 = 32 * wv + mq * 4 + r;
      out[((size_t)b * C_ + row0) * N_ + pp] = acc0[r] + bo[0][r];
      out[((size_t)b * C_ + row0 + 16) * N_ + pp] = acc1[r] + bo[1][r];
    }
  };

  stage_write(ldA, 0);
  __syncthreads();
#pragma unroll
  for (int l = 0; l < 4; ++l) ldB[l] = *(const float4*)(xsrc + 32 + (size_t)l * N_);
  compute(0);
  compute(1);
  stage_write(ldB, 32);                            // waits vmcnt here, after MFMA
  __syncthreads();
  compute(2);
  compute(3);
}

extern "C" void kernel_launch(void* const* d_in, const int* in_sizes, int n_in,
                              void* d_out, int out_size, void* d_ws, size_t ws_size,
                              hipStream_t stream) {
  const float* xin    = (const float*)d_in[0];
  const float* wsplit = (const float*)d_in[1];
  const float* wq     = (const float*)d_in[2];
  const float* wk     = (const float*)d_in[3];
  const float* wv     = (const float*)d_in[4];
  const float* wproj  = (const float*)d_in[5];
  const float* bproj  = (const float*)d_in[6];
  const float* wout   = (const float*)d_in[7];
  float* out = (float*)d_out;

  float* ws = (float*)d_ws;
  float* G     = ws;                         // B*CC2
  float* Wq    = G + (size_t)B_ * CC2;       // CC2
  float* WqT   = Wq + CC2;
  float* Wk    = WqT + CC2;
  float* Wv    = Wk + CC2;
  float* Wo2   = Wv + CC2;
  float* bias2 = Wo2 + CC2;                  // 256
  float* Tk    = bias2 + 256;                // B*CC2
  float* Tv    = Tk + (size_t)B_ * CC2;
  float* Mw    = Tv + (size_t)B_ * CC2;
  float* qn    = Mw + (size_t)B_ * CC2;      // B*C_ (pad 256)
  float* P     = qn + 256 * B_;              // B*NCHUNK*CC2 (37.7 MB) if it fits

  size_t base_floats = (size_t)(P - ws);
  size_t need_bytes = (base_floats + (size_t)B_ * NCHUNK * CC2) * sizeof(float);
  bool use_partials = ws_size >= need_bytes;

  fold_kernel<<<(4 * CC2 + 255) / 256, 256, 0, stream>>>(
      wsplit, wq, wk, wv, wproj, bproj, wout, Wq, WqT, Wk, Wv, Wo2, bias2);
  if (use_partials) {
    gram3_kernel<false><<<dim3(NCHUNK, 2, B_), 384, 0, stream>>>(xin, P);
    gsum_kernel<<<dim3(CC2 / 1024, B_), 256, 0, stream>>>(P, G);
  } else {
    hipMemsetAsync(G, 0, (size_t)B_ * CC2 * sizeof(float), stream);
    gram3_kernel<true><<<dim3(NCHUNK, 2, B_), 384, 0, stream>>>(xin, G);
  }
  tkqn_kernel<<<dim3(C_, B_), 192, 0, stream>>>(Wk, Wq, G, Tk, qn);
  attn_av_kernel<<<dim3(C_, B_), 192, 0, stream>>>(Tk, WqT, Wk, Wv, qn, Tv);
  m_kernel<<<(B_ * CC2 + 255) / 256, 256, 0, stream>>>(Wo2, Tv, Mw);
  final3_kernel<<<dim3(N_ / 64, B_), 384, 0, stream>>>(xin, Mw, bias2, out);
}